// Round 6
// baseline (264.123 us; speedup 1.0000x reference)
//
#include <hip/hip_runtime.h>

// VEConv: E=800000, N=50000, RBF=100, D=64. E % 64 == 0 (12500 tiles of 64).
// Round 6: persistent blocks + 2-stage software pipeline.
//  - GRID=512 persistent blocks, each owns tiles bid, bid+512, ... (~24 tiles)
//  - weights staged to LDS once per block (single barrier in whole kernel)
//  - rotated pipeline: top of iteration consumes NEXT regs (loads issued one
//    iteration earlier -> HBM latency hidden under previous compute), then
//    issues tile i+1 loads, then computes. Loads cross the loop back-edge so
//    the compiler cannot sink them to uses (round-5 failure mode, VGPR=60).
//  - node gathers issued at compute start, consumed at epilogue (~800 cy later)
//  - round-3 contiguous-dim f32-atomic epilogue (measured cheap in round 4)
#define RBF_DIM 100
#define PGRID 512

typedef __attribute__((ext_vector_type(8))) short bf16x8;
typedef __attribute__((ext_vector_type(4))) float f32x4;

__device__ __forceinline__ unsigned short f2bf(float f) {
    union { float f; unsigned int u; } v; v.f = f;
    unsigned int r = (v.u + 0x7FFFu + ((v.u >> 16) & 1u)) >> 16;
    return (unsigned short)r;
}
__device__ __forceinline__ bf16x8 cvt8(f32x4 a, f32x4 b) {
    bf16x8 r;
    r[0] = (short)f2bf(a[0]); r[1] = (short)f2bf(a[1]);
    r[2] = (short)f2bf(a[2]); r[3] = (short)f2bf(a[3]);
    r[4] = (short)f2bf(b[0]); r[5] = (short)f2bf(b[1]);
    r[6] = (short)f2bf(b[2]); r[7] = (short)f2bf(b[3]);
    return r;
}

// ---- pre-kernel: weights as bf16 MFMA fragments, dump order ----
// ws ushort layout: 32 frags x 64 lanes x 8 elems
//   f in [0,16):  W1T frag (t4=f>>2, ks=f&3), k=32ks+8g+j (k=100 -> b1, >100 -> 0)
//   f in [16,24): W2T frag (t4=(f-16)>>1, ks=(f-16)&1)
//   f in [24,32): W3T frag (t4=(f-24)>>1, ks=(f-24)&1)
__global__ void prep_weights(const float* __restrict__ W1, const float* __restrict__ b1,
                             const float* __restrict__ W2, const float* __restrict__ W3,
                             unsigned short* __restrict__ ws) {
    for (int e = threadIdx.x; e < 32 * 64 * 8; e += 256) {
        int f = e >> 9;
        int lane = (e >> 3) & 63;
        int j = e & 7;
        int l15 = lane & 15, g = lane >> 4;
        float v;
        if (f < 16) {
            int t4 = f >> 2, ks = f & 3;
            int k = 32 * ks + 8 * g + j, o = 16 * t4 + l15;
            v = (k < RBF_DIM) ? W1[k * 64 + o] : ((k == RBF_DIM) ? b1[o] : 0.0f);
        } else if (f < 24) {
            int q = f - 16, t4 = q >> 1, ks = q & 1;
            int k = 32 * ks + 8 * g + j, o = 16 * t4 + l15;
            v = W2[k * 64 + o];
        } else {
            int q = f - 24, t4 = q >> 1, ks = q & 1;
            int k = 32 * ks + 8 * g + j, o = 16 * t4 + l15;
            v = W3[k * 64 + o];
        }
        ws[e] = f2bf(v);
    }
}

__global__ __launch_bounds__(256, 2)
void veconv_main(const float* __restrict__ rbf, const float* __restrict__ edge_f,
                 const float* __restrict__ node,
                 const float* __restrict__ b2, const float* __restrict__ b3,
                 const int* __restrict__ src, const int* __restrict__ dst,
                 const unsigned short* __restrict__ wsw,
                 float* __restrict__ out, int ntiles) {
    __shared__ unsigned short wlds[32 * 512];      // 32 KB fragment-ordered weights
    __shared__ unsigned short sp_lds[4 * 16 * 64]; // 8 KB softplus transpose (per-wave)

    const int tid = threadIdx.x;
    const int lane = tid & 63, wid = tid >> 6;
    const int l15 = lane & 15, g = lane >> 4;
    const int swz = (l15 & 7) << 3;

    // ---- stage weights to LDS once ----
    {
        const uint4* wg = (const uint4*)wsw;
        uint4* wl = (uint4*)wlds;
#pragma unroll
        for (int i = 0; i < 8; ++i) wl[tid + 256 * i] = wg[tid + 256 * i];
    }
    float b2v[4], b3v[4];
#pragma unroll
    for (int t4 = 0; t4 < 4; ++t4) { b2v[t4] = b2[16 * t4 + l15]; b3v[t4] = b3[16 * t4 + l15]; }
    __syncthreads();
    const bf16x8* frg = (const bf16x8*)wlds;

    // ---- persistent tile loop, 2-stage rotated pipeline ----
    const int bid = blockIdx.x;
    const int nt = ntiles / PGRID + (bid < (ntiles % PGRID) ? 1 : 0);
    if (nt == 0) return;
    long tile = bid;

    // NEXT registers (held across the back-edge)
    f32x4 nr0, nr1, nr2, nr3, nr4, nr5, nrt;
    f32x4 ne0, ne1, ne2, ne3;
    int4 nsrc4, ndst4;

    // prologue: issue loads for first tile
    {
        const float* rrow = rbf + (tile * 64 + wid * 16 + l15) * RBF_DIM;
        nr0 = *(const f32x4*)(rrow + 8 * g);      nr1 = *(const f32x4*)(rrow + 8 * g + 4);
        nr2 = *(const f32x4*)(rrow + 32 + 8 * g); nr3 = *(const f32x4*)(rrow + 32 + 8 * g + 4);
        nr4 = *(const f32x4*)(rrow + 64 + 8 * g); nr5 = *(const f32x4*)(rrow + 64 + 8 * g + 4);
        if (g == 0) nrt = *(const f32x4*)(rrow + 96);
        const float* erow = edge_f + (tile * 64 + wid * 16 + l15) * 64;
        ne0 = *(const f32x4*)(erow + 8 * g);      ne1 = *(const f32x4*)(erow + 8 * g + 4);
        ne2 = *(const f32x4*)(erow + 32 + 8 * g); ne3 = *(const f32x4*)(erow + 32 + 8 * g + 4);
        nsrc4 = *(const int4*)(src + tile * 64 + wid * 16 + 4 * g);
        ndst4 = *(const int4*)(dst + tile * 64 + wid * 16 + 4 * g);
    }

    for (int i = 0; i < nt; ++i) {
        // ---- consume NEXT -> current (this is where the vmcnt waits land) ----
        bf16x8 bfk0 = cvt8(nr0, nr1);
        bf16x8 bfk1 = cvt8(nr2, nr3);
        bf16x8 bfk2 = cvt8(nr4, nr5);
        bf16x8 bfk3 = (bf16x8){0, 0, 0, 0, 0, 0, 0, 0};
        if (g == 0) {
            bfk3[0] = (short)f2bf(nrt[0]); bfk3[1] = (short)f2bf(nrt[1]);
            bfk3[2] = (short)f2bf(nrt[2]); bfk3[3] = (short)f2bf(nrt[3]);
            bfk3[4] = (short)0x3F80;   // k=100 bias-1.0 column
        }
        bf16x8 ae0 = cvt8(ne0, ne1);
        bf16x8 ae1 = cvt8(ne2, ne3);
        const int sv0 = nsrc4.x, sv1 = nsrc4.y, sv2 = nsrc4.z, sv3 = nsrc4.w;
        const int dv0 = ndst4.x, dv1 = ndst4.y, dv2 = ndst4.z, dv3 = ndst4.w;

        // ---- issue node gathers for current tile (consumed at epilogue) ----
        float ndv0[4], ndv1[4], ndv2[4], ndv3[4];
#pragma unroll
        for (int t4 = 0; t4 < 4; ++t4) {
            ndv0[t4] = node[(long)sv0 * 64 + 16 * t4 + l15];
            ndv1[t4] = node[(long)sv1 * 64 + 16 * t4 + l15];
            ndv2[t4] = node[(long)sv2 * 64 + 16 * t4 + l15];
            ndv3[t4] = node[(long)sv3 * 64 + 16 * t4 + l15];
        }

        // ---- issue NEXT tile loads (latency hidden under this tile's compute) ----
        tile += PGRID;
        if (i + 1 < nt) {
            const float* rrow = rbf + (tile * 64 + wid * 16 + l15) * RBF_DIM;
            nr0 = *(const f32x4*)(rrow + 8 * g);      nr1 = *(const f32x4*)(rrow + 8 * g + 4);
            nr2 = *(const f32x4*)(rrow + 32 + 8 * g); nr3 = *(const f32x4*)(rrow + 32 + 8 * g + 4);
            nr4 = *(const f32x4*)(rrow + 64 + 8 * g); nr5 = *(const f32x4*)(rrow + 64 + 8 * g + 4);
            if (g == 0) nrt = *(const f32x4*)(rrow + 96);
            const float* erow = edge_f + (tile * 64 + wid * 16 + l15) * 64;
            ne0 = *(const f32x4*)(erow + 8 * g);      ne1 = *(const f32x4*)(erow + 8 * g + 4);
            ne2 = *(const f32x4*)(erow + 32 + 8 * g); ne3 = *(const f32x4*)(erow + 32 + 8 * g + 4);
            nsrc4 = *(const int4*)(src + tile * 64 + wid * 16 + 4 * g);
            ndst4 = *(const int4*)(dst + tile * 64 + wid * 16 + 4 * g);
        }

        // ---- GEMM1: D1[d][e] = W1T @ rbf^T ----
        f32x4 acc1[4];
#pragma unroll
        for (int t4 = 0; t4 < 4; ++t4) acc1[t4] = (f32x4){0.f, 0.f, 0.f, 0.f};
#pragma unroll
        for (int t4 = 0; t4 < 4; ++t4) {
            acc1[t4] = __builtin_amdgcn_mfma_f32_16x16x32_bf16(frg[(t4 * 4 + 0) * 64 + lane], bfk0, acc1[t4], 0, 0, 0);
            acc1[t4] = __builtin_amdgcn_mfma_f32_16x16x32_bf16(frg[(t4 * 4 + 1) * 64 + lane], bfk1, acc1[t4], 0, 0, 0);
            acc1[t4] = __builtin_amdgcn_mfma_f32_16x16x32_bf16(frg[(t4 * 4 + 2) * 64 + lane], bfk2, acc1[t4], 0, 0, 0);
            acc1[t4] = __builtin_amdgcn_mfma_f32_16x16x32_bf16(frg[(t4 * 4 + 3) * 64 + lane], bfk3, acc1[t4], 0, 0, 0);
        }

        // ---- softplus(beta=0.5, thr=14) -> sp_lds (own-wave region, no barrier) ----
        // D1 layout: lane (g,l15) holds col e=l15, rows d = 16*t4 + 4*g + r
#pragma unroll
        for (int t4 = 0; t4 < 4; ++t4) {
            float spv[4];
#pragma unroll
            for (int r = 0; r < 4; ++r) {
                float x = acc1[t4][r];
                float bx = 0.5f * x;
                float s = 2.0f * __logf(1.0f + __expf(bx));
                spv[r] = (bx > 14.0f) ? x : s;
            }
            unsigned int p0 = (unsigned int)f2bf(spv[0]) | ((unsigned int)f2bf(spv[1]) << 16);
            unsigned int p1 = (unsigned int)f2bf(spv[2]) | ((unsigned int)f2bf(spv[3]) << 16);
            int el = (wid * 16 + l15) * 64 + ((16 * t4 + 4 * g) ^ swz);
            *(uint2*)&sp_lds[el] = make_uint2(p0, p1);
        }

        // ---- GEMM2/3 swapped operands: D[e][d] edge-major ----
        f32x4 acc2[4], acc3[4];
#pragma unroll
        for (int t4 = 0; t4 < 4; ++t4) {
            acc2[t4] = (f32x4){0.f, 0.f, 0.f, 0.f};
            acc3[t4] = (f32x4){0.f, 0.f, 0.f, 0.f};
        }
#pragma unroll
        for (int ks = 0; ks < 2; ++ks) {
            bf16x8 asp = *(const bf16x8*)&sp_lds[(wid * 16 + l15) * 64 + ((32 * ks + 8 * g) ^ swz)];
            bf16x8 ae = (ks == 0) ? ae0 : ae1;
#pragma unroll
            for (int t4 = 0; t4 < 4; ++t4) {
                acc2[t4] = __builtin_amdgcn_mfma_f32_16x16x32_bf16(asp, frg[(16 + t4 * 2 + ks) * 64 + lane], acc2[t4], 0, 0, 0);
                acc3[t4] = __builtin_amdgcn_mfma_f32_16x16x32_bf16(ae,  frg[(24 + t4 * 2 + ks) * 64 + lane], acc3[t4], 0, 0, 0);
            }
        }
        // acc2/acc3: lane (g,l15) holds edge 4g+r, dim 16*t4+l15

        // ---- epilogue: contiguous-dim atomic scatter from accumulators ----
        {
            float* o0 = out + (long)dv0 * 64 + l15;
            float* o1 = out + (long)dv1 * 64 + l15;
            float* o2 = out + (long)dv2 * 64 + l15;
            float* o3 = out + (long)dv3 * 64 + l15;
#pragma unroll
            for (int t4 = 0; t4 < 4; ++t4) {
                atomicAdd(&o0[16 * t4], ndv0[t4] * (acc2[t4][0] + b2v[t4]) + (acc3[t4][0] + b3v[t4]));
                atomicAdd(&o1[16 * t4], ndv1[t4] * (acc2[t4][1] + b2v[t4]) + (acc3[t4][1] + b3v[t4]));
                atomicAdd(&o2[16 * t4], ndv2[t4] * (acc2[t4][2] + b2v[t4]) + (acc3[t4][2] + b3v[t4]));
                atomicAdd(&o3[16 * t4], ndv3[t4] * (acc2[t4][3] + b2v[t4]) + (acc3[t4][3] + b3v[t4]));
            }
        }
    }
}

extern "C" void kernel_launch(void* const* d_in, const int* in_sizes, int n_in,
                              void* d_out, int out_size, void* d_ws, size_t ws_size,
                              hipStream_t stream) {
    const float* rbf    = (const float*)d_in[0];
    const float* edge_f = (const float*)d_in[1];
    const float* node   = (const float*)d_in[2];
    const float* W1     = (const float*)d_in[3];
    const float* b1     = (const float*)d_in[4];
    const float* W2     = (const float*)d_in[5];
    const float* b2     = (const float*)d_in[6];
    const float* W3     = (const float*)d_in[7];
    const float* b3     = (const float*)d_in[8];
    const int*   src    = (const int*)d_in[9];
    const int*   dst    = (const int*)d_in[10];
    float* out = (float*)d_out;
    unsigned short* ws = (unsigned short*)d_ws;

    const int E = in_sizes[9];              // 800000, divisible by 64
    const int ntiles = E / 64;              // 12500
    const int grid = (ntiles < PGRID) ? ntiles : PGRID;

    hipMemsetAsync(d_out, 0, (size_t)out_size * sizeof(float), stream);
    prep_weights<<<1, 256, 0, stream>>>(W1, b1, W2, W3, ws);
    veconv_main<<<grid, 256, 0, stream>>>(rbf, edge_f, node, b2, b3, src, dst, ws, out, ntiles);
}

// Round 7
// 223.814 us; speedup vs baseline: 1.1801x; 1.1801x over previous
//
#include <hip/hip_runtime.h>

// VEConv: E=800000, N=50000, RBF=100, D=64. E % 128 == 0 (6250 blocks of 128).
// Round 7: round-5 structure (it was the best: 218 us), plus
//  (1) hardware v_cvt_pk_bf16_f32 for ALL f32->bf16 (round-6 arithmetic showed
//      ~2.5k VALU cyc/wave-tile, dominated by software round-to-nearest),
//  (2) 512-thread blocks: 8 waves share one 32 KiB weight tile -> 48 KiB LDS
//      per block -> 3 blocks/CU -> 24 waves/CU (75%) vs round-5's 16 (43%).
//  No persistent loop, no register pipeline (round 6 showed it halves
//  occupancy and breaks L3 locality for a net loss).
#define RBF_DIM 100

typedef __attribute__((ext_vector_type(8))) short bf16x8;
typedef __attribute__((ext_vector_type(4))) float f32x4;

// software RNE (host-side prep kernel only; runs once on 1 block)
__device__ __forceinline__ unsigned short f2bf_sw(float f) {
    union { float f; unsigned int u; } v; v.f = f;
    unsigned int r = (v.u + 0x7FFFu + ((v.u >> 16) & 1u)) >> 16;
    return (unsigned short)r;
}

// hardware packed cvt: lo16 = bf16(x), hi16 = bf16(y), RNE
__device__ __forceinline__ unsigned int cvtpk(float x, float y) {
    unsigned int r;
    asm("v_cvt_pk_bf16_f32 %0, %1, %2" : "=v"(r) : "v"(x), "v"(y));
    return r;
}
__device__ __forceinline__ bf16x8 cvt8(f32x4 a, f32x4 b) {
    union { bf16x8 v; unsigned int u[4]; } r;
    r.u[0] = cvtpk(a[0], a[1]);
    r.u[1] = cvtpk(a[2], a[3]);
    r.u[2] = cvtpk(b[0], b[1]);
    r.u[3] = cvtpk(b[2], b[3]);
    return r.v;
}

// ---- pre-kernel: weights as bf16 MFMA fragments, dump order ----
// ws ushort layout: 32 frags x 64 lanes x 8 elems
//   f in [0,16):  W1T frag (t4=f>>2, ks=f&3), k=32ks+8g+j (k=100 -> b1, >100 -> 0)
//   f in [16,24): W2T frag (t4=(f-16)>>1, ks=(f-16)&1)
//   f in [24,32): W3T frag (t4=(f-24)>>1, ks=(f-24)&1)
__global__ void prep_weights(const float* __restrict__ W1, const float* __restrict__ b1,
                             const float* __restrict__ W2, const float* __restrict__ W3,
                             unsigned short* __restrict__ ws) {
    for (int e = threadIdx.x; e < 32 * 64 * 8; e += 256) {
        int f = e >> 9;
        int lane = (e >> 3) & 63;
        int j = e & 7;
        int l15 = lane & 15, g = lane >> 4;
        float v;
        if (f < 16) {
            int t4 = f >> 2, ks = f & 3;
            int k = 32 * ks + 8 * g + j, o = 16 * t4 + l15;
            v = (k < RBF_DIM) ? W1[k * 64 + o] : ((k == RBF_DIM) ? b1[o] : 0.0f);
        } else if (f < 24) {
            int q = f - 16, t4 = q >> 1, ks = q & 1;
            int k = 32 * ks + 8 * g + j, o = 16 * t4 + l15;
            v = W2[k * 64 + o];
        } else {
            int q = f - 24, t4 = q >> 1, ks = q & 1;
            int k = 32 * ks + 8 * g + j, o = 16 * t4 + l15;
            v = W3[k * 64 + o];
        }
        ws[e] = f2bf_sw(v);
    }
}

// ---- main fused kernel: 128 edges/block, 8 waves x 16 edges ----
__global__ __launch_bounds__(512, 4)
void veconv_main(const float* __restrict__ rbf, const float* __restrict__ edge_f,
                 const float* __restrict__ node,
                 const float* __restrict__ b2, const float* __restrict__ b3,
                 const int* __restrict__ src, const int* __restrict__ dst,
                 const unsigned short* __restrict__ wsw,
                 float* __restrict__ out) {
    __shared__ unsigned short wlds[32 * 512];      // 32 KB fragment-ordered weights
    __shared__ unsigned short sp_lds[8 * 16 * 64]; // 16 KB softplus transpose (per-wave)

    const int tid = threadIdx.x;
    const int lane = tid & 63, wid = tid >> 6;     // wid in [0,8)
    const int l15 = lane & 15, g = lane >> 4;
    const int ew0 = blockIdx.x * 128 + wid * 16;
    const int eg = ew0 + l15;
    const int swz = (l15 & 7) << 3;

    // ---- burst-issue global loads ----
    const float* rrow = rbf + (long)eg * RBF_DIM;
    const f32x4 ra0 = *(const f32x4*)(rrow + 8 * g);
    const f32x4 ra1 = *(const f32x4*)(rrow + 8 * g + 4);
    const f32x4 rb0 = *(const f32x4*)(rrow + 32 + 8 * g);
    const f32x4 rb1 = *(const f32x4*)(rrow + 32 + 8 * g + 4);
    const f32x4 rc0 = *(const f32x4*)(rrow + 64 + 8 * g);
    const f32x4 rc1 = *(const f32x4*)(rrow + 64 + 8 * g + 4);
    f32x4 rt = (f32x4){0.f, 0.f, 0.f, 0.f};
    if (g == 0) rt = *(const f32x4*)(rrow + 96);
    const float* erow = edge_f + (long)eg * 64;
    const f32x4 ea0 = *(const f32x4*)(erow + 8 * g);
    const f32x4 ea1 = *(const f32x4*)(erow + 8 * g + 4);
    const f32x4 eb0 = *(const f32x4*)(erow + 32 + 8 * g);
    const f32x4 eb1 = *(const f32x4*)(erow + 32 + 8 * g + 4);
    const int4 s4 = *(const int4*)(src + ew0 + 4 * g);
    const int4 d4 = *(const int4*)(dst + ew0 + 4 * g);
    float b2v[4], b3v[4];
#pragma unroll
    for (int t4 = 0; t4 < 4; ++t4) { b2v[t4] = b2[16 * t4 + l15]; b3v[t4] = b3[16 * t4 + l15]; }

    // ---- stage weights to LDS (cooperative, coalesced, 4 uint4/thread) ----
    {
        const uint4* wg = (const uint4*)wsw;
        uint4* wl = (uint4*)wlds;
#pragma unroll
        for (int i = 0; i < 4; ++i) wl[tid + 512 * i] = wg[tid + 512 * i];
    }

    // ---- node gathers (depend only on s4) ----
    const int sv[4] = {s4.x, s4.y, s4.z, s4.w};
    const int dv[4] = {d4.x, d4.y, d4.z, d4.w};
    float nd[4][4];
#pragma unroll
    for (int r = 0; r < 4; ++r)
#pragma unroll
        for (int t4 = 0; t4 < 4; ++t4)
            nd[r][t4] = node[(long)sv[r] * 64 + 16 * t4 + l15];

    __syncthreads();   // weights visible to all waves

    const bf16x8* frg = (const bf16x8*)wlds;  // frag f, lane: frg[f*64 + lane]

    // ---- GEMM1: D1[d][e] = W1T @ rbf^T ----
    bf16x8 bfk[4];
    bfk[0] = cvt8(ra0, ra1);
    bfk[1] = cvt8(rb0, rb1);
    bfk[2] = cvt8(rc0, rc1);
    {
        union { bf16x8 v; unsigned int u[4]; } bt;
        bt.u[0] = (g == 0) ? cvtpk(rt[0], rt[1]) : 0u;
        bt.u[1] = (g == 0) ? cvtpk(rt[2], rt[3]) : 0u;
        bt.u[2] = (g == 0) ? 0x3F80u : 0u;   // k=100 bias-1.0 column (lo16)
        bt.u[3] = 0u;
        bfk[3] = bt.v;
    }
    f32x4 acc1[4];
#pragma unroll
    for (int t4 = 0; t4 < 4; ++t4) acc1[t4] = (f32x4){0.f, 0.f, 0.f, 0.f};
#pragma unroll
    for (int ks = 0; ks < 4; ++ks)
#pragma unroll
        for (int t4 = 0; t4 < 4; ++t4)
            acc1[t4] = __builtin_amdgcn_mfma_f32_16x16x32_bf16(frg[(t4 * 4 + ks) * 64 + lane],
                                                               bfk[ks], acc1[t4], 0, 0, 0);

    // ---- softplus(beta=0.5, thr=14) -> sp_lds (own-wave region, no barrier) ----
    // D1 layout: lane (g,l15) holds col e=l15, rows d = 16*t4 + 4*g + r
#pragma unroll
    for (int t4 = 0; t4 < 4; ++t4) {
        float spv[4];
#pragma unroll
        for (int r = 0; r < 4; ++r) {
            float x = acc1[t4][r];
            float bx = 0.5f * x;
            float s = 2.0f * __logf(1.0f + __expf(bx));
            spv[r] = (bx > 14.0f) ? x : s;
        }
        unsigned int p0 = cvtpk(spv[0], spv[1]);
        unsigned int p1 = cvtpk(spv[2], spv[3]);
        int el = (wid * 16 + l15) * 64 + ((16 * t4 + 4 * g) ^ swz);
        *(uint2*)&sp_lds[el] = make_uint2(p0, p1);
    }

    // ---- GEMM2/3 swapped operands: D[e][d] edge-major ----
    bf16x8 aef[2];
    aef[0] = cvt8(ea0, ea1);
    aef[1] = cvt8(eb0, eb1);
    f32x4 acc2[4], acc3[4];
#pragma unroll
    for (int t4 = 0; t4 < 4; ++t4) {
        acc2[t4] = (f32x4){0.f, 0.f, 0.f, 0.f};
        acc3[t4] = (f32x4){0.f, 0.f, 0.f, 0.f};
    }
#pragma unroll
    for (int ks = 0; ks < 2; ++ks) {
        bf16x8 asp = *(const bf16x8*)&sp_lds[(wid * 16 + l15) * 64 + ((32 * ks + 8 * g) ^ swz)];
#pragma unroll
        for (int t4 = 0; t4 < 4; ++t4) {
            acc2[t4] = __builtin_amdgcn_mfma_f32_16x16x32_bf16(asp,
                          frg[(16 + t4 * 2 + ks) * 64 + lane], acc2[t4], 0, 0, 0);
            acc3[t4] = __builtin_amdgcn_mfma_f32_16x16x32_bf16(aef[ks],
                          frg[(24 + t4 * 2 + ks) * 64 + lane], acc3[t4], 0, 0, 0);
        }
    }
    // acc2/acc3: lane (g,l15) holds edge 4g+r, dim 16*t4+l15

    // ---- epilogue: contiguous-dim atomic scatter from accumulators ----
#pragma unroll
    for (int r = 0; r < 4; ++r) {
        float* orow = out + (long)dv[r] * 64 + l15;
#pragma unroll
        for (int t4 = 0; t4 < 4; ++t4) {
            float msg = nd[r][t4] * (acc2[t4][r] + b2v[t4]) + (acc3[t4][r] + b3v[t4]);
            atomicAdd(&orow[16 * t4], msg);
        }
    }
}

extern "C" void kernel_launch(void* const* d_in, const int* in_sizes, int n_in,
                              void* d_out, int out_size, void* d_ws, size_t ws_size,
                              hipStream_t stream) {
    const float* rbf    = (const float*)d_in[0];
    const float* edge_f = (const float*)d_in[1];
    const float* node   = (const float*)d_in[2];
    const float* W1     = (const float*)d_in[3];
    const float* b1     = (const float*)d_in[4];
    const float* W2     = (const float*)d_in[5];
    const float* b2     = (const float*)d_in[6];
    const float* W3     = (const float*)d_in[7];
    const float* b3     = (const float*)d_in[8];
    const int*   src    = (const int*)d_in[9];
    const int*   dst    = (const int*)d_in[10];
    float* out = (float*)d_out;
    unsigned short* ws = (unsigned short*)d_ws;

    const int E = in_sizes[9];              // 800000, divisible by 128

    hipMemsetAsync(d_out, 0, (size_t)out_size * sizeof(float), stream);
    prep_weights<<<1, 256, 0, stream>>>(W1, b1, W2, W3, ws);
    veconv_main<<<E / 128, 512, 0, stream>>>(rbf, edge_f, node, b2, b3, src, dst, ws, out);
}